// Round 4
// baseline (29361.508 us; speedup 1.0000x reference)
//
#include <hip/hip_runtime.h>
#include <cstdint>
#include <cstddef>

#define SEQ 512
#define BAT 64
#define DIM 1024
#define HID 1024
#define NLAYER 2
#define NGATE 4096  // 4*HID
#define EPS_LN 1e-5f
#define KSPLIT 12
#define PART_STRIDE (BAT * NGATE)  // 262144
#define LO_SCALE 4096.0f           // 2^12: keeps f16 low-order terms normal
#define LO_INV (1.0f / 4096.0f)

typedef __attribute__((ext_vector_type(8))) _Float16 f16x8;
typedef __attribute__((ext_vector_type(4))) float f32x4;

__device__ __forceinline__ unsigned short f2h(float f) {
    _Float16 h = (_Float16)f;             // round-to-nearest
    unsigned short u; __builtin_memcpy(&u, &h, 2); return u;
}
__device__ __forceinline__ float h2f(unsigned short u) {
    _Float16 h; __builtin_memcpy(&h, &u, 2); return (float)h;
}

// ---------------- setup ----------------

__global__ void init_hc_kernel(const float* __restrict__ h0,
                               const float* __restrict__ c0,
                               float* __restrict__ hbuf,
                               float* __restrict__ cbuf) {
    int i = blockIdx.x * blockDim.x + threadIdx.x;
    hbuf[i] = h0[i];
    cbuf[i] = c0[i];
}

// ---------------- one-time weight split + MFMA-fragment pack ----------------
// Packed layout per array (layer,mat,part): [nt=256][kc=32][lane=64][j=8] f16.
// Lane l reading (nt,kc) gets W[kc*32 + 8*(l>>4)+j][nt*16 + (l&15)] == the
// B-fragment of v_mfma_f32_16x16x32_f16. part0 = f16(W); part1 = f16(2^12 *
// (W - part0)) -- scaled so it stays in f16 normal range.
__global__ __launch_bounds__(256) void prepack_w_kernel(
    const float* __restrict__ wx, const float* __restrict__ wh,
    unsigned short* __restrict__ wp)
{
    int gid = blockIdx.x * 256 + threadIdx.x;   // 2,097,152 threads
    int lane = gid & 63;
    int kc   = (gid >> 6) & 31;
    int nt   = (gid >> 11) & 255;
    int mat  = (gid >> 19) & 1;
    int l    = (gid >> 20) & 1;
    const float* src = (mat ? wh : wx) + (size_t)l * ((size_t)DIM * NGATE);
    int col = nt * 16 + (lane & 15);
    int kr0 = kc * 32 + 8 * (lane >> 4);
    unsigned hp[4], lp[4];
    #pragma unroll
    for (int i = 0; i < 4; i++) {
        float v0 = src[(size_t)(kr0 + 2 * i) * NGATE + col];
        float v1 = src[(size_t)(kr0 + 2 * i + 1) * NGATE + col];
        unsigned short h0 = f2h(v0), h1 = f2h(v1);
        unsigned short l0 = f2h(LO_SCALE * (v0 - h2f(h0)));
        unsigned short l1 = f2h(LO_SCALE * (v1 - h2f(h1)));
        hp[i] = (unsigned)h0 | ((unsigned)h1 << 16);
        lp[i] = (unsigned)l0 | ((unsigned)l1 << 16);
    }
    size_t inner = (((size_t)nt * 32 + kc) * 64 + lane) * 8;
    unsigned short* dh = wp + (((size_t)(l * 4 + mat * 2 + 0)) << 22) + inner;
    unsigned short* dl = wp + (((size_t)(l * 4 + mat * 2 + 1)) << 22) + inner;
    *(uint4*)dh = make_uint4(hp[0], hp[1], hp[2], hp[3]);
    *(uint4*)dl = make_uint4(lp[0], lp[1], lp[2], lp[3]);
}

// ---------------- per-step gates GEMM via f16x3 MFMA (latency-tolerant) ----
// C[64,4096] = A[64,2048]*W[2048,4096], A=concat(x_t,h). Terms:
//   a1*w1 + a2'*w1/2^12 (DUAL blocks, W1 read once, two accumulators)
// + a1*w2'/2^12         (single blocks)
// Grid (64 n-blocks of 64 cols, 12 k-blocks). kb 0..7: W1 (x:0-3, h:4-7),
// K=256 per block. kb 8..11: W2 (x:8-9, h:10-11), K=512.
// Block: 256 thr / 4 waves; wave owns 32 rows x 32 cols (2x2 16x16 frags).
// One-shot LDS stage (<=64KB) -> single barrier -> barrier-free K-loop with
// 2-deep W register double-buffer (W never touches LDS).
template<bool DUAL>
__device__ __forceinline__ void gates_body(
    const float* __restrict__ A0, const float* __restrict__ A1,
    const unsigned short* __restrict__ wpl, float* __restrict__ part,
    unsigned short* __restrict__ abuf)
{
    constexpr int KLEN = DUAL ? 256 : 512;
    constexpr int G = KLEN / 32;          // k-chunks of 32
    const int ntb = blockIdx.x;           // 0..63
    const int kb  = blockIdx.y;           // 0..11
    int mat, k0;
    if (DUAL) { mat = kb >> 2;       k0 = (kb & 3) * 256; }
    else      { mat = (kb >> 1) & 1; k0 = (kb & 1) * 512; }
    const float* __restrict__ Asrc = mat ? A1 : A0;
    const unsigned short* __restrict__ Wbase =
        wpl + (((size_t)(mat * 2 + (DUAL ? 0 : 1))) << 22);

    const int tid  = threadIdx.x;
    const int lane = tid & 63;
    const int w    = tid >> 6;
    const int m0w  = (w >> 1) * 32;
    const int nh   = w & 1;
    const int lrow = lane & 15;
    const int lg   = lane >> 4;

    unsigned short* __restrict__ alo = abuf + 64 * 256;  // DUAL only (32KB in)

    // ---- one-shot stage: A[64][KLEN] fp32 -> f16 hi (+scaled lo), swizzled --
    {
        const int sr = tid >> 2;                 // row 0..63
        const int sq = (tid & 3) * (KLEN / 4);   // col base
        const float* s = Asrc + (size_t)sr * 1024 + k0 + sq;
        const unsigned rowb = (unsigned)sr * (KLEN * 2);
        const unsigned sw = (unsigned)((sr & 7) << 4);
        #pragma unroll
        for (int j = 0; j < KLEN / 32; j++) {    // 8 elems per iter
            float4 a = *(const float4*)(s + 8 * j);
            float4 b = *(const float4*)(s + 8 * j + 4);
            unsigned short h[8];
            h[0] = f2h(a.x); h[1] = f2h(a.y); h[2] = f2h(a.z); h[3] = f2h(a.w);
            h[4] = f2h(b.x); h[5] = f2h(b.y); h[6] = f2h(b.z); h[7] = f2h(b.w);
            uint4 hv = make_uint4((unsigned)h[0] | ((unsigned)h[1] << 16),
                                  (unsigned)h[2] | ((unsigned)h[3] << 16),
                                  (unsigned)h[4] | ((unsigned)h[5] << 16),
                                  (unsigned)h[6] | ((unsigned)h[7] << 16));
            unsigned off = (rowb + (unsigned)(sq + 8 * j) * 2) ^ sw;
            *(uint4*)((char*)abuf + off) = hv;
            if (DUAL) {
                unsigned short l[8];
                l[0] = f2h(LO_SCALE * (a.x - h2f(h[0])));
                l[1] = f2h(LO_SCALE * (a.y - h2f(h[1])));
                l[2] = f2h(LO_SCALE * (a.z - h2f(h[2])));
                l[3] = f2h(LO_SCALE * (a.w - h2f(h[3])));
                l[4] = f2h(LO_SCALE * (b.x - h2f(h[4])));
                l[5] = f2h(LO_SCALE * (b.y - h2f(h[5])));
                l[6] = f2h(LO_SCALE * (b.z - h2f(h[6])));
                l[7] = f2h(LO_SCALE * (b.w - h2f(h[7])));
                uint4 lv = make_uint4((unsigned)l[0] | ((unsigned)l[1] << 16),
                                      (unsigned)l[2] | ((unsigned)l[3] << 16),
                                      (unsigned)l[4] | ((unsigned)l[5] << 16),
                                      (unsigned)l[6] | ((unsigned)l[7] << 16));
                *(uint4*)((char*)alo + off) = lv;
            }
        }
    }
    __syncthreads();

    // ---- barrier-free K-loop, 2-deep W register double-buffer ----
    const size_t kcg0 = (size_t)(k0 >> 5);
    const int ntgb = ntb * 4 + nh * 2;          // global 16-col tile base
    f32x4 acc[2][2], accl[2][2];
    #pragma unroll
    for (int mi = 0; mi < 2; mi++)
        #pragma unroll
        for (int ni = 0; ni < 2; ni++) {
            acc[mi][ni]  = (f32x4){0.f, 0.f, 0.f, 0.f};
            accl[mi][ni] = (f32x4){0.f, 0.f, 0.f, 0.f};
        }

    f16x8 wv[2][2];
    auto wload = [&](int g, int buf) {
        #pragma unroll
        for (int ni = 0; ni < 2; ni++)
            wv[buf][ni] = *(const f16x8*)(Wbase +
                (((size_t)(ntgb + ni) * 32 + kcg0 + (size_t)g) * 64 + lane) * 8);
    };
    wload(0, 0);

    #pragma unroll
    for (int g = 0; g < G; g++) {
        if (g + 1 < G) wload(g + 1, (g + 1) & 1);
        f16x8 ah[2], al[2];
        #pragma unroll
        for (int mi = 0; mi < 2; mi++) {
            int row = m0w + mi * 16 + lrow;
            unsigned off = (unsigned)row * (KLEN * 2) +
                           (((unsigned)(g * 64 + lg * 16)) ^ ((unsigned)(row & 7) << 4));
            ah[mi] = *(const f16x8*)((const char*)abuf + off);
            if (DUAL) al[mi] = *(const f16x8*)((const char*)alo + off);
        }
        const int b = g & 1;
        #pragma unroll
        for (int mi = 0; mi < 2; mi++)
            #pragma unroll
            for (int ni = 0; ni < 2; ni++) {
                acc[mi][ni] = __builtin_amdgcn_mfma_f32_16x16x32_f16(
                    ah[mi], wv[b][ni], acc[mi][ni], 0, 0, 0);
                if (DUAL)
                    accl[mi][ni] = __builtin_amdgcn_mfma_f32_16x16x32_f16(
                        al[mi], wv[b][ni], accl[mi][ni], 0, 0, 0);
            }
    }

    float* __restrict__ pp = part + (size_t)kb * PART_STRIDE;
    #pragma unroll
    for (int mi = 0; mi < 2; mi++)
        #pragma unroll
        for (int ni = 0; ni < 2; ni++) {
            int brow = m0w + mi * 16 + 4 * lg;
            int col  = ntb * 64 + nh * 32 + ni * 16 + lrow;
            #pragma unroll
            for (int r = 0; r < 4; r++) {
                float v = DUAL ? (acc[mi][ni][r] + accl[mi][ni][r] * LO_INV)
                               : (acc[mi][ni][r] * LO_INV);
                pp[(size_t)(brow + r) * NGATE + col] = v;
            }
        }
}

__global__ __launch_bounds__(256, 2) void gates_mfma_kernel(
    const float* __restrict__ A0,   // [64][1024] fp32 (x_t or y_prev_t)
    const float* __restrict__ A1,   // [64][1024] fp32 (h)
    const unsigned short* __restrict__ wpl,  // packed weights, layer base
    float* __restrict__ part)       // [12][64][4096]
{
    __shared__ __align__(16) unsigned short abuf[64 * 512];  // 64 KiB
    if (blockIdx.y < 8) gates_body<true>(A0, A1, wpl, part, abuf);
    else                gates_body<false>(A0, A1, wpl, part, abuf);
}

// ---------------- per-step LN + cell update ----------------
__global__ __launch_bounds__(1024) void update_kernel(
    const float* __restrict__ part,    // [12][64][4096]
    const float* __restrict__ bias,    // [4096]  (layer slice)
    const float* __restrict__ gamma,   // [4][1024]
    const float* __restrict__ beta,    // [4][1024]
    float* __restrict__ cbuf,          // [64][1024]
    float* __restrict__ hbuf,          // [64][1024]
    float* __restrict__ y_out,         // d_out ys slot t
    float* __restrict__ hs_out,        // t==S-1: d_out hs slot, else null
    float* __restrict__ cs_out)
{
    int b = blockIdx.x;
    int j = threadIdx.x;
    float raw[4], s[4], q[4];
    #pragma unroll
    for (int g = 0; g < 4; g++) {
        int col = g * 1024 + j;
        float v = bias[col];
        #pragma unroll
        for (int p = 0; p < KSPLIT; p++)
            v += part[(size_t)p * PART_STRIDE + (size_t)b * 4096 + col];
        raw[g] = v; s[g] = v; q[g] = v * v;
    }
    #pragma unroll
    for (int off = 32; off > 0; off >>= 1) {
        #pragma unroll
        for (int g = 0; g < 4; g++) {
            s[g] += __shfl_down(s[g], off);
            q[g] += __shfl_down(q[g], off);
        }
    }
    __shared__ float red[16][8];
    __shared__ float stats[8];
    int wave = j >> 6, lane = j & 63;
    if (lane == 0) {
        #pragma unroll
        for (int g = 0; g < 4; g++) { red[wave][g] = s[g]; red[wave][4 + g] = q[g]; }
    }
    __syncthreads();
    if (j == 0) {
        float ts[8] = {0,0,0,0,0,0,0,0};
        for (int w = 0; w < 16; w++)
            for (int g = 0; g < 8; g++) ts[g] += red[w][g];
        #pragma unroll
        for (int g = 0; g < 4; g++) {
            float mu  = ts[g] * (1.0f / 1024.0f);
            float var = ts[4 + g] * (1.0f / 1024.0f) - mu * mu;
            stats[g] = mu;
            stats[4 + g] = rsqrtf(fmaxf(var, 0.0f) + EPS_LN);
        }
    }
    __syncthreads();
    float gh[4];
    #pragma unroll
    for (int g = 0; g < 4; g++) {
        int col = g * 1024 + j;
        gh[g] = (raw[g] - stats[g]) * stats[4 + g] * gamma[col] + beta[col];
    }
    float c_old = cbuf[b * 1024 + j];
    float ig = 1.f / (1.f + __expf(-gh[0]));
    float fg = 1.f / (1.f + __expf(-gh[1]));
    float og = 1.f / (1.f + __expf(-gh[2]));
    float c_new = fg * c_old + ig * tanhf(gh[3]);
    float h_new = og * tanhf(c_new);
    cbuf[b * 1024 + j] = c_new;
    hbuf[b * 1024 + j] = h_new;
    y_out[b * 1024 + j] = h_new;
    if (hs_out) { hs_out[b * 1024 + j] = h_new; cs_out[b * 1024 + j] = c_new; }
}

// ---------------- launch ----------------

extern "C" void kernel_launch(void* const* d_in, const int* in_sizes, int n_in,
                              void* d_out, int out_size, void* d_ws, size_t ws_size,
                              hipStream_t stream) {
    const float* inputs = (const float*)d_in[0]; // (512,64,1024)
    const float* h0     = (const float*)d_in[1]; // (2,64,1024)
    const float* c0     = (const float*)d_in[2]; // (2,64,1024)
    const float* wx     = (const float*)d_in[3]; // (2,1024,4096)
    const float* wh     = (const float*)d_in[4]; // (2,1024,4096)
    const float* bias   = (const float*)d_in[5]; // (2,4096)
    const float* gamma  = (const float*)d_in[6]; // (2,4,1024)
    const float* beta   = (const float*)d_in[7]; // (2,4,1024)
    float* dout = (float*)d_out;

    // workspace: packed f16 weights 64 MiB + part 12 MiB + h/c 1 MiB = 77 MiB
    unsigned short* wp = (unsigned short*)d_ws;
    float* part = (float*)(wp + ((size_t)8 << 22));
    float* hbuf = part + (size_t)KSPLIT * PART_STRIDE;
    float* cbuf = hbuf + NLAYER * BAT * HID;

    prepack_w_kernel<<<8192, 256, 0, stream>>>(wx, wh, wp);
    init_hc_kernel<<<512, 256, 0, stream>>>(h0, c0, hbuf, cbuf);

    const int BH = BAT * HID;         // 65536
    const int XOUT = SEQ * BAT * HID; // 33,554,432
    for (int t = 0; t < SEQ; t++) {
        for (int l = 0; l < NLAYER; l++) {
            const float* a0 = (l == 0) ? (inputs + (size_t)t * BH)
                                       : (dout + (size_t)t * BH);
            gates_mfma_kernel<<<dim3(64, KSPLIT), 256, 0, stream>>>(
                a0, hbuf + l * BH, wp + ((size_t)l << 24), part);
            update_kernel<<<64, 1024, 0, stream>>>(
                part,
                bias + l * 4096, gamma + l * 4096, beta + l * 4096,
                cbuf + l * BH, hbuf + l * BH,
                dout + (size_t)t * BH,
                (t == SEQ - 1) ? (dout + XOUT + l * BH) : nullptr,
                (t == SEQ - 1) ? (dout + XOUT + NLAYER * BH + l * BH) : nullptr);
        }
    }
}